// Round 1
// baseline (1478.290 us; speedup 1.0000x reference)
//
#include <hip/hip_runtime.h>

// ---------- helpers ----------
typedef _Float16 half8 __attribute__((ext_vector_type(8)));

__device__ __forceinline__ unsigned short f2bf(float f) {
  unsigned u = __float_as_uint(f);
  u += 0x7FFFu + ((u >> 16) & 1u);
  return (unsigned short)(u >> 16);
}
__device__ __forceinline__ float bf2f(unsigned short b) {
  return __uint_as_float(((unsigned)b) << 16);
}
__device__ __forceinline__ float sigf(float x) {
  return __builtin_amdgcn_rcpf(1.f + __expf(-x));
}
__device__ __forceinline__ float tanhf_(float x) {
  float t = __expf(2.f * x);
  return 1.f - 2.f * __builtin_amdgcn_rcpf(t + 1.f);  // NaN-free for t in [0, inf]
}

#define NROWS 32832   // 513 seqs * 64 steps

// ---------- K0: repack concat_w into cw4[k4][d][4] ----------
__global__ __launch_bounds__(256)
void k0_cw4(const float* __restrict__ cw, float* __restrict__ cw4) {
  int idx = blockIdx.x * 256 + threadIdx.x;
  if (idx < 320000) {
    int d = idx / 1600, k = idx % 1600;
    cw4[(size_t)(k >> 2) * 800 + d * 4 + (k & 3)] = cw[idx];
  }
}

// ---------- K1: gather emb rows + input projection GEMM (f32) ----------
// XP[r][0:400] = wih_f @ x_r + bih_f + bhh_f ; XP[r][400:800] same with _b. bf16 out.
__global__ __launch_bounds__(128)
void k1_proj(const int* __restrict__ head_toks, const int* __restrict__ body_toks,
             const float* __restrict__ emb,
             const float* __restrict__ wihf, const float* __restrict__ wihb,
             const float* __restrict__ bihf, const float* __restrict__ bhhf,
             const float* __restrict__ bihb, const float* __restrict__ bhhb,
             unsigned short* __restrict__ XP) {
  __shared__ float At[32][132];
  __shared__ float Wt[32][132];
  __shared__ int toks[128];
  const int tid = threadIdx.x;
  const int r0 = blockIdx.x * 128;
  const int c0 = blockIdx.y * 128;
  if (tid < 128) {
    int r = r0 + tid;
    int tok = 0;
    if (r < NROWS) {
      int u = r >> 6, t = r & 63;
      tok = (u < 512) ? body_toks[u * 64 + t] : head_toks[t];
    }
    toks[tid] = tok;
  }
  const int ty = tid >> 3;  // 0..15 -> rows ty*8..+7
  const int tx = tid & 7;   // 0..7  -> cols tx*4 + q*32 + j
  float acc[8][16];
#pragma unroll
  for (int i = 0; i < 8; ++i)
#pragma unroll
    for (int j = 0; j < 16; ++j) acc[i][j] = 0.f;

  for (int k0 = 0; k0 < 300; k0 += 32) {
    __syncthreads();
#pragma unroll
    for (int it = 0; it < 8; ++it) {  // stage A (gathered, transposed)
      int slot = tid + it * 128;
      int rr = slot >> 3, kq = slot & 7;
      int k = k0 + kq * 4;
      float4 v = make_float4(0.f, 0.f, 0.f, 0.f);
      if (k < 300) v = *(const float4*)(emb + (size_t)toks[rr] * 300 + k);
      At[kq * 4 + 0][rr] = v.x; At[kq * 4 + 1][rr] = v.y;
      At[kq * 4 + 2][rr] = v.z; At[kq * 4 + 3][rr] = v.w;
    }
#pragma unroll
    for (int it = 0; it < 8; ++it) {  // stage W (transposed)
      int slot = tid + it * 128;
      int cc = slot >> 3, kq = slot & 7;
      int gc = c0 + cc;
      int k = k0 + kq * 4;
      float4 v = make_float4(0.f, 0.f, 0.f, 0.f);
      if (k < 300 && gc < 800) {
        const float* wp = (gc < 400) ? (wihf + (size_t)gc * 300)
                                     : (wihb + (size_t)(gc - 400) * 300);
        v = *(const float4*)(wp + k);
      }
      Wt[kq * 4 + 0][cc] = v.x; Wt[kq * 4 + 1][cc] = v.y;
      Wt[kq * 4 + 2][cc] = v.z; Wt[kq * 4 + 3][cc] = v.w;
    }
    __syncthreads();
#pragma unroll 4
    for (int k = 0; k < 32; ++k) {
      float a[8], b[16];
      *(float4*)&a[0] = *(const float4*)&At[k][ty * 8];
      *(float4*)&a[4] = *(const float4*)&At[k][ty * 8 + 4];
#pragma unroll
      for (int q = 0; q < 4; ++q)
        *(float4*)&b[q * 4] = *(const float4*)&Wt[k][tx * 4 + q * 32];
#pragma unroll
      for (int i = 0; i < 8; ++i)
#pragma unroll
        for (int j = 0; j < 16; ++j)
          acc[i][j] = fmaf(a[i], b[j], acc[i][j]);
    }
  }
  float biasv[16];
#pragma unroll
  for (int j = 0; j < 16; ++j) {
    int gc = c0 + tx * 4 + (j >> 2) * 32 + (j & 3);
    float bv = 0.f;
    if (gc < 400) bv = bihf[gc] + bhhf[gc];
    else if (gc < 800) bv = bihb[gc - 400] + bhhb[gc - 400];
    biasv[j] = bv;
  }
#pragma unroll
  for (int i = 0; i < 8; ++i) {
    int r = r0 + ty * 8 + i;
    if (r >= NROWS) continue;
#pragma unroll
    for (int q = 0; q < 4; ++q) {
      int colq = c0 + tx * 4 + q * 32;
      if (colq >= 800) continue;
      ushort4 pk;
      pk.x = f2bf(acc[i][q * 4 + 0] + biasv[q * 4 + 0]);
      pk.y = f2bf(acc[i][q * 4 + 1] + biasv[q * 4 + 1]);
      pk.z = f2bf(acc[i][q * 4 + 2] + biasv[q * 4 + 2]);
      pk.w = f2bf(acc[i][q * 4 + 3] + biasv[q * 4 + 3]);
      *(ushort4*)(XP + (size_t)r * 800 + colq) = pk;
    }
  }
}

// ---------- K2: recurrent LSTM (one wave per (seq,dir) unit) ----------
#define K2_W2_SLOTS (4 * 2 * 13 * 64)                    // 6656 x 16B frag slots
#define K2_LDS_BYTES (K2_W2_SLOTS * 16 + 5 * 104 * 4)    // 108576

__global__ __launch_bounds__(320)
void k2_lstm(const unsigned short* __restrict__ XP,
             const float* __restrict__ whhf, const float* __restrict__ whhb,
             float* __restrict__ sentRM, float* __restrict__ sentT,
             float* __restrict__ dout) {
  extern __shared__ char smem[];
  _Float16* W2 = (_Float16*)smem;
  float* hall = (float*)(smem + K2_W2_SLOTS * 16);
  const int tid = threadIdx.x;
  const int wave = tid >> 6;
  const int lane = tid & 63;
  const int wg = blockIdx.x;
  const bool fwd = wg < 128;
  const int wg2 = fwd ? wg : wg - 128;
  const float* whh = fwd ? whhf : whhb;

  // Stage whh as f16 in fragment order: slot((g,ms,kb))[lane] = whh[g*100 + ms*64+lane][kb*8..+7]
  for (int idx = tid; idx < K2_W2_SLOTS; idx += 320) {
    int lane_s = idx & 63;
    int kb = (idx >> 6) % 13;
    int gm = idx / (13 * 64);   // (g*2+ms)
    int m = (gm & 1) * 64 + lane_s;
    int g = gm >> 1;
    half8 hv;
#pragma unroll
    for (int i = 0; i < 8; ++i) {
      int k = kb * 8 + i;
      float v = 0.f;
      if (m < 100 && k < 100) v = whh[(size_t)(g * 100 + m) * 100 + k];
      hv[i] = (_Float16)v;
    }
    *(half8*)(W2 + (size_t)idx * 8) = hv;
  }

  int u;
  if (wave < 4) u = wg2 * 4 + wave;
  else u = (wg2 == 0) ? 512 : -1;   // 5th wave = head unit only in wg 0 / 128

  float* hme = hall + wave * 104;
  if (u >= 0) {
    for (int i = lane; i < 104; i += 64) hme[i] = 0.f;
  }
  __syncthreads();
  if (u < 0) return;
  // no barriers from here on: each wave owns its private h region

  const int off = fwd ? 0 : 400;
  const int doff = fwd ? 0 : 100;
  const int ubase = u * 64;
  const int mm0 = lane;
  const bool v1 = (64 + lane) < 100;
  const int mm1 = v1 ? 64 + lane : 0;

  unsigned short xp[4][2];
  {
    int r = ubase + (fwd ? 0 : 63);
    const unsigned short* rp = XP + (size_t)r * 800 + off;
#pragma unroll
    for (int g = 0; g < 4; ++g) { xp[g][0] = rp[g * 100 + mm0]; xp[g][1] = rp[g * 100 + mm1]; }
  }
  float c0 = 0.f, c1 = 0.f, hl0 = 0.f, hl1 = 0.f;

  for (int t = 0; t < 64; ++t) {
    float acc[4][2];
#pragma unroll
    for (int g = 0; g < 4; ++g) { acc[g][0] = bf2f(xp[g][0]); acc[g][1] = bf2f(xp[g][1]); }
    {   // prefetch next step's XP row
      int tn = (t + 1 < 64) ? t + 1 : 63;
      int r = ubase + (fwd ? tn : 63 - tn);
      const unsigned short* rp = XP + (size_t)r * 800 + off;
#pragma unroll
      for (int g = 0; g < 4; ++g) { xp[g][0] = rp[g * 100 + mm0]; xp[g][1] = rp[g * 100 + mm1]; }
    }
#pragma unroll
    for (int kb = 0; kb < 13; ++kb) {
      float hv[8];
      *(float4*)&hv[0] = *(const float4*)(hme + kb * 8);
      *(float4*)&hv[4] = *(const float4*)(hme + kb * 8 + 4);
#pragma unroll
      for (int g = 0; g < 4; ++g)
#pragma unroll
        for (int ms = 0; ms < 2; ++ms) {
          half8 w = *(const half8*)(W2 + ((size_t)((g * 2 + ms) * 13 + kb) * 64 + lane) * 8);
          float a = acc[g][ms];
#pragma unroll
          for (int i = 0; i < 8; ++i) a = fmaf((float)w[i], hv[i], a);
          acc[g][ms] = a;
        }
    }
    {
      float si = sigf(acc[0][0]), sf = sigf(acc[1][0]), so = sigf(acc[3][0]);
      float tg = tanhf_(acc[2][0]);
      c0 = sf * c0 + si * tg;
      hl0 = so * tanhf_(c0);
      hme[mm0] = hl0;
    }
    if (v1) {
      float si = sigf(acc[0][1]), sf = sigf(acc[1][1]), so = sigf(acc[3][1]);
      float tg = tanhf_(acc[2][1]);
      c1 = sf * c1 + si * tg;
      hl1 = so * tanhf_(c1);
      hme[64 + lane] = hl1;
    }
  }
  {
    int d = doff + mm0;
    sentRM[(size_t)u * 200 + d] = hl0;
    sentT[(size_t)d * 520 + u] = hl0;
    if (u == 512) dout[200 + d] = hl0;
  }
  if (v1) {
    int d = doff + 64 + lane;
    sentRM[(size_t)u * 200 + d] = hl1;
    sentT[(size_t)d * 520 + u] = hl1;
    if (u == 512) dout[200 + d] = hl1;
  }
}

// ---------- K3: Q/K/V projections. QT,KT stored [h][e][s]; V stored [h][t][e] ----------
__global__ __launch_bounds__(256)
void k3_qkv(const float* __restrict__ sentT,
            const float* __restrict__ wq, const float* __restrict__ bq,
            const float* __restrict__ wk, const float* __restrict__ bk,
            const float* __restrict__ wv, const float* __restrict__ bv,
            float* __restrict__ QT, float* __restrict__ KT, float* __restrict__ V) {
  __shared__ float slds[32 * 64];
  __shared__ float wt[32 * 204];
  const int tid = threadIdx.x;
  const int mat = blockIdx.x;
  const int h = blockIdx.y;
  const int s0 = blockIdx.z * 64;
  const float* W = (mat == 0) ? wq : (mat == 1) ? wk : wv;
  const float* B = (mat == 0) ? bq : (mat == 1) ? bk : bv;
  W += (size_t)h * 40000;
  B += h * 200;
  const int ts = (tid < 200) ? tid / 25 : 0;
  const int te = (tid < 200) ? tid % 25 : 0;
  float acc[8][8];
#pragma unroll
  for (int i = 0; i < 8; ++i)
#pragma unroll
    for (int j = 0; j < 8; ++j) acc[i][j] = 0.f;

  for (int d0 = 0; d0 < 200; d0 += 32) {
    __syncthreads();
#pragma unroll
    for (int it = 0; it < 8; ++it) {
      int idx = tid + it * 256;
      int dd = idx >> 6, sl = idx & 63;
      int d = d0 + dd;
      slds[idx] = (d < 200) ? sentT[(size_t)d * 520 + s0 + sl] : 0.f;
    }
    for (int idx = tid; idx < 1600; idx += 256) {
      int dq = idx / 200, e = idx % 200;
      int d = d0 + dq * 4;
      float4 v = make_float4(0.f, 0.f, 0.f, 0.f);
      if (d < 200) v = *(const float4*)(W + (size_t)e * 200 + d);
      wt[(dq * 4 + 0) * 204 + e] = v.x; wt[(dq * 4 + 1) * 204 + e] = v.y;
      wt[(dq * 4 + 2) * 204 + e] = v.z; wt[(dq * 4 + 3) * 204 + e] = v.w;
    }
    __syncthreads();
    if (tid < 200) {
#pragma unroll 4
      for (int dd = 0; dd < 32; ++dd) {
        float a[8], b[8];
        *(float4*)&a[0] = *(const float4*)&slds[dd * 64 + ts * 8];
        *(float4*)&a[4] = *(const float4*)&slds[dd * 64 + ts * 8 + 4];
        *(float4*)&b[0] = *(const float4*)&wt[dd * 204 + te * 8];
        *(float4*)&b[4] = *(const float4*)&wt[dd * 204 + te * 8 + 4];
#pragma unroll
        for (int i = 0; i < 8; ++i)
#pragma unroll
          for (int j = 0; j < 8; ++j) acc[i][j] = fmaf(a[i], b[j], acc[i][j]);
      }
    }
  }
  if (tid < 200) {
    if (mat < 2) {
      float* O = (mat == 0) ? QT : KT;
#pragma unroll
      for (int j = 0; j < 8; ++j) {
        int e = te * 8 + j;
        float bb = B[e];
        float vals[8];
#pragma unroll
        for (int i = 0; i < 8; ++i) vals[i] = acc[i][j] + bb;
        float* p = O + (size_t)h * 102400 + (size_t)e * 512 + s0 + ts * 8;
        *(float4*)&p[0] = *(float4*)&vals[0];
        *(float4*)&p[4] = *(float4*)&vals[4];
      }
    } else {
#pragma unroll
      for (int i = 0; i < 8; ++i) {
        float vals[8];
#pragma unroll
        for (int j = 0; j < 8; ++j) vals[j] = acc[i][j] + B[te * 8 + j];
        float* p = V + (size_t)h * 102400 + (size_t)(s0 + ts * 8 + i) * 200 + te * 8;
        *(float4*)&p[0] = *(float4*)&vals[0];
        *(float4*)&p[4] = *(float4*)&vals[4];
      }
    }
  }
}

// ---------- K4: SIMT[h][t][s] = Q[h,s,:] . K[h,t,:] (raw, scale folded into softmax) ----------
__global__ __launch_bounds__(128)
void k4_sim(const float* __restrict__ QT, const float* __restrict__ KT,
            float* __restrict__ SIMT) {
  __shared__ float kt[32 * 64];
  __shared__ float qt[32 * 64];
  const int tid = threadIdx.x;
  const int s0 = blockIdx.x * 64;
  const int t0 = blockIdx.y * 64;
  const int h = blockIdx.z;
  const int tt = tid & 15, ss = tid >> 4;
  float acc[4][8];
#pragma unroll
  for (int i = 0; i < 4; ++i)
#pragma unroll
    for (int j = 0; j < 8; ++j) acc[i][j] = 0.f;
  for (int e0 = 0; e0 < 200; e0 += 32) {
    __syncthreads();
#pragma unroll
    for (int it = 0; it < 16; ++it) {
      int idx = tid + it * 128;
      int ee = idx >> 6, tl = idx & 63;
      int e = e0 + ee;
      kt[idx] = (e < 200) ? KT[(size_t)h * 102400 + (size_t)e * 512 + t0 + tl] : 0.f;
      qt[idx] = (e < 200) ? QT[(size_t)h * 102400 + (size_t)e * 512 + s0 + tl] : 0.f;
    }
    __syncthreads();
#pragma unroll 4
    for (int ee = 0; ee < 32; ++ee) {
      float a[4], b[8];
      *(float4*)&a[0] = *(const float4*)&kt[ee * 64 + tt * 4];
      *(float4*)&b[0] = *(const float4*)&qt[ee * 64 + ss * 8];
      *(float4*)&b[4] = *(const float4*)&qt[ee * 64 + ss * 8 + 4];
#pragma unroll
      for (int i = 0; i < 4; ++i)
#pragma unroll
        for (int j = 0; j < 8; ++j) acc[i][j] = fmaf(a[i], b[j], acc[i][j]);
    }
  }
#pragma unroll
  for (int i = 0; i < 4; ++i) {
    float* p = SIMT + ((size_t)h * 512 + t0 + tt * 4 + i) * 512 + s0 + ss * 8;
    *(float4*)&p[0] = *(float4*)&acc[i][0];
    *(float4*)&p[4] = *(float4*)&acc[i][4];
  }
}

// ---------- K5: softmax over s (contiguous rows of SIMT), in place ----------
__global__ __launch_bounds__(256)
void k5_softmax(float* __restrict__ SIMT) {
  const int tid = threadIdx.x;
  const int row = blockIdx.x * 4 + (tid >> 6);
  const int lane = tid & 63;
  float* p = SIMT + (size_t)row * 512 + lane * 8;
  float4 a = *(float4*)p, b = *(float4*)(p + 4);
  const float sc = 0.07071067811865475f;  // 1/sqrt(200)
  float v[8] = {a.x, a.y, a.z, a.w, b.x, b.y, b.z, b.w};
#pragma unroll
  for (int i = 0; i < 8; ++i) v[i] *= sc;
  float m = v[0];
#pragma unroll
  for (int i = 1; i < 8; ++i) m = fmaxf(m, v[i]);
  for (int d = 1; d < 64; d <<= 1) m = fmaxf(m, __shfl_xor(m, d, 64));
  float sum = 0.f;
#pragma unroll
  for (int i = 0; i < 8; ++i) { v[i] = __expf(v[i] - m); sum += v[i]; }
  for (int d = 1; d < 64; d <<= 1) sum += __shfl_xor(sum, d, 64);
  float inv = __builtin_amdgcn_rcpf(sum);
  a = make_float4(v[0] * inv, v[1] * inv, v[2] * inv, v[3] * inv);
  b = make_float4(v[4] * inv, v[5] * inv, v[6] * inv, v[7] * inv);
  *(float4*)p = a;
  *(float4*)(p + 4) = b;
}

// ---------- K6: OUT[h][s][e] = sum_t ATT[h][t][s] * V[h][t][e] ----------
__global__ __launch_bounds__(256)
void k6_av(const float* __restrict__ ATT, const float* __restrict__ V,
           float* __restrict__ OUTb) {
  __shared__ float attl[64 * 36];
  __shared__ float vl[64 * 204];
  const int tid = threadIdx.x;
  const int s0 = blockIdx.x * 32;
  const int h = blockIdx.y;
  const int ts = (tid < 200) ? tid / 25 : 0;  // s = s0 + ts*4 + i
  const int te = (tid < 200) ? tid % 25 : 0;  // e = te*8 + j
  float acc[4][8];
#pragma unroll
  for (int i = 0; i < 4; ++i)
#pragma unroll
    for (int j = 0; j < 8; ++j) acc[i][j] = 0.f;
  for (int t0 = 0; t0 < 512; t0 += 64) {
    __syncthreads();
#pragma unroll
    for (int it = 0; it < 8; ++it) {
      int idx = tid + it * 256;
      int tl = idx >> 5, sl = idx & 31;
      attl[tl * 36 + sl] = ATT[((size_t)h * 512 + t0 + tl) * 512 + s0 + sl];
    }
    for (int idx = tid; idx < 12800; idx += 256) {
      int tl = idx / 200, e = idx % 200;
      vl[tl * 204 + e] = V[(size_t)h * 102400 + (size_t)(t0 + tl) * 200 + e];
    }
    __syncthreads();
    if (tid < 200) {
#pragma unroll 2
      for (int tl = 0; tl < 64; ++tl) {
        float a[4], b[8];
        *(float4*)&a[0] = *(const float4*)&attl[tl * 36 + ts * 4];
        *(float4*)&b[0] = *(const float4*)&vl[tl * 204 + te * 8];
        *(float4*)&b[4] = *(const float4*)&vl[tl * 204 + te * 8 + 4];
#pragma unroll
        for (int i = 0; i < 4; ++i)
#pragma unroll
          for (int j = 0; j < 8; ++j) acc[i][j] = fmaf(a[i], b[j], acc[i][j]);
      }
    }
  }
  if (tid < 200) {
#pragma unroll
    for (int i = 0; i < 4; ++i) {
      float* p = OUTb + (size_t)h * 102400 + (size_t)(s0 + ts * 4 + i) * 200 + te * 8;
      *(float4*)&p[0] = *(float4*)&acc[i][0];
      *(float4*)&p[4] = *(float4*)&acc[i][4];
    }
  }
}

// ---------- K7: multi[s][d] = concat_b[d] + sum_k hc[s][k]*concat_w[d][k] ----------
__global__ __launch_bounds__(256)
void k7_multi(const float* __restrict__ OUTb, const float* __restrict__ cw4,
              const float* __restrict__ concat_b, float* __restrict__ multi) {
  __shared__ float hc[1600];
  const int tid = threadIdx.x;
  const int s = blockIdx.x;
  for (int idx = tid; idx < 1600; idx += 256) {
    int h = idx / 200, e = idx % 200;
    hc[idx] = OUTb[(size_t)h * 102400 + (size_t)s * 200 + e];
  }
  __syncthreads();
  if (tid < 200) {
    float a = concat_b[tid];
    const float4* cp = (const float4*)cw4 + tid;
    const float4* hp = (const float4*)hc;
    for (int k4 = 0; k4 < 400; ++k4) {
      float4 w = cp[(size_t)k4 * 200];
      float4 x = hp[k4];
      a = fmaf(w.x, x.x, a); a = fmaf(w.y, x.y, a);
      a = fmaf(w.z, x.z, a); a = fmaf(w.w, x.w, a);
    }
    multi[(size_t)s * 200 + tid] = a;
  }
}

// ---------- K8: high_sent_feature[d] = feat_b[d] + feat_w[d,:] . multi_flat ----------
__global__ __launch_bounds__(256)
void k8_feat(const float* __restrict__ feat_w, const float* __restrict__ feat_b,
             const float* __restrict__ multi, float* __restrict__ dout) {
  __shared__ float red[4];
  const int tid = threadIdx.x;
  const int d = blockIdx.x;
  const float4* fw = (const float4*)(feat_w + (size_t)d * 102400);
  const float4* mf = (const float4*)multi;
  float a = 0.f;
  for (int i = tid; i < 25600; i += 256) {
    float4 w = fw[i], x = mf[i];
    a = fmaf(w.x, x.x, a); a = fmaf(w.y, x.y, a);
    a = fmaf(w.z, x.z, a); a = fmaf(w.w, x.w, a);
  }
  for (int m_ = 1; m_ < 64; m_ <<= 1) a += __shfl_xor(a, m_, 64);
  if ((tid & 63) == 0) red[tid >> 6] = a;
  __syncthreads();
  if (tid == 0) dout[d] = red[0] + red[1] + red[2] + red[3] + feat_b[d];
}

// ---------- K9: TextCNN conv (same-correlation, pad w-1 both sides on S) + maxpool ----------
struct ConvPtrs { const float* p[7]; };

__global__ __launch_bounds__(256)
void k9_conv(ConvPtrs cp, const float* __restrict__ conv_b,
             const float* __restrict__ sent, float* __restrict__ dout) {
  __shared__ float cwl[7 * 200];
  __shared__ float wmax[4];
  const int tid = threadIdx.x;
  const int wi = blockIdx.x;       // window idx 0..6, w = wi+1
  const int f = blockIdx.y;        // filter 0..9
  const int w = wi + 1;
  const float* cw = cp.p[wi] + (size_t)f * w * 200;
  for (int idx = tid; idx < w * 200; idx += 256) cwl[idx] = cw[idx];
  __syncthreads();
  const int wave = tid >> 6, lane = tid & 63;
  float best = -3.4e38f;
  for (int jj = wave; jj < 512 + w - 1; jj += 4) {
    float part = 0.f;
    for (int k = 0; k < w; ++k) {
      int r = jj + k - (w - 1);
      if (r >= 0 && r < 512) {
        const float* sr = sent + (size_t)r * 200;
        const float* cr = cwl + k * 200;
        for (int d = lane; d < 200; d += 64) part = fmaf(cr[d], sr[d], part);
      }
    }
    for (int m_ = 1; m_ < 64; m_ <<= 1) part += __shfl_xor(part, m_, 64);
    best = fmaxf(best, part);
  }
  if (lane == 0) wmax[wave] = best;
  __syncthreads();
  if (tid == 0) {
    float m = fmaxf(fmaxf(wmax[0], wmax[1]), fmaxf(wmax[2], wmax[3]));
    dout[400 + wi * 10 + f] = m + conv_b[wi * 10 + f];
  }
}

// ---------- host ----------
extern "C" void kernel_launch(void* const* d_in, const int* in_sizes, int n_in,
                              void* d_out, int out_size, void* d_ws, size_t ws_size,
                              hipStream_t stream) {
  (void)in_sizes; (void)n_in; (void)out_size; (void)ws_size;
  const int*   head_toks = (const int*)d_in[0];
  const int*   body_toks = (const int*)d_in[1];
  const float* emb      = (const float*)d_in[2];
  const float* wih_f    = (const float*)d_in[3];
  const float* whh_f    = (const float*)d_in[4];
  const float* bih_f    = (const float*)d_in[5];
  const float* bhh_f    = (const float*)d_in[6];
  const float* wih_b    = (const float*)d_in[7];
  const float* whh_b    = (const float*)d_in[8];
  const float* bih_b    = (const float*)d_in[9];
  const float* bhh_b    = (const float*)d_in[10];
  const float* wq       = (const float*)d_in[11];
  const float* bq       = (const float*)d_in[12];
  const float* wk       = (const float*)d_in[13];
  const float* bk       = (const float*)d_in[14];
  const float* wv       = (const float*)d_in[15];
  const float* bv       = (const float*)d_in[16];
  const float* concat_w = (const float*)d_in[17];
  const float* concat_b = (const float*)d_in[18];
  const float* feat_w   = (const float*)d_in[19];
  const float* feat_b   = (const float*)d_in[20];
  const float* conv_b   = (const float*)d_in[21];
  float* out = (float*)d_out;
  char* ws = (char*)d_ws;

  size_t off = 0;
  auto take = [&](size_t b) { size_t o = off; off += (b + 255) & ~(size_t)255; return o; };
  unsigned short* XP = (unsigned short*)(ws + take(32832UL * 800 * 2));
  float* sentRM = (float*)(ws + take(513UL * 200 * 4));
  float* sentT  = (float*)(ws + take(200UL * 520 * 4));
  float* QT     = (float*)(ws + take(8UL * 200 * 512 * 4));
  float* KT     = (float*)(ws + take(8UL * 200 * 512 * 4));
  float* Vb     = (float*)(ws + take(8UL * 512 * 200 * 4));
  float* SIMT   = (float*)(ws + take(8UL * 512 * 512 * 4));
  float* OUTb   = (float*)(ws + take(8UL * 512 * 200 * 4));
  float* multi  = (float*)(ws + take(512UL * 200 * 4));
  float* cw4    = (float*)(ws + take(1600UL * 200 * 4));

  k0_cw4<<<1250, 256, 0, stream>>>(concat_w, cw4);
  k1_proj<<<dim3(257, 7), 128, 0, stream>>>(head_toks, body_toks, emb,
                                            wih_f, wih_b, bih_f, bhh_f, bih_b, bhh_b, XP);
  static bool attr_set = []() {
    hipFuncSetAttribute(reinterpret_cast<const void*>(k2_lstm),
                        hipFuncAttributeMaxDynamicSharedMemorySize, 160 * 1024);
    return true;
  }();
  (void)attr_set;
  k2_lstm<<<256, 320, K2_LDS_BYTES, stream>>>(XP, whh_f, whh_b, sentRM, sentT, out);
  k3_qkv<<<dim3(3, 8, 8), 256, 0, stream>>>(sentT, wq, bq, wk, bk, wv, bv, QT, KT, Vb);
  k4_sim<<<dim3(8, 8, 8), 128, 0, stream>>>(QT, KT, SIMT);
  k5_softmax<<<1024, 256, 0, stream>>>(SIMT);
  k6_av<<<dim3(16, 8), 256, 0, stream>>>(SIMT, Vb, OUTb);
  k7_multi<<<512, 256, 0, stream>>>(OUTb, cw4, concat_b, multi);
  k8_feat<<<200, 256, 0, stream>>>(feat_w, feat_b, multi, out);
  ConvPtrs cps;
  for (int i = 0; i < 7; ++i) cps.p[i] = (const float*)d_in[22 + i];
  k9_conv<<<dim3(7, 10), 256, 0, stream>>>(cps, conv_b, sentRM, out);
}

// Round 2
// 1401.309 us; speedup vs baseline: 1.0549x; 1.0549x over previous
//
#include <hip/hip_runtime.h>

// ---------- helpers ----------
typedef _Float16 half8 __attribute__((ext_vector_type(8)));
typedef _Float16 half4 __attribute__((ext_vector_type(4)));
typedef float f32x4 __attribute__((ext_vector_type(4)));

__device__ __forceinline__ float sigf(float x) {
  return __builtin_amdgcn_rcpf(1.f + __expf(-x));
}
__device__ __forceinline__ float tanhf_(float x) {
  float t = __expf(2.f * x);
  return 1.f - 2.f * __builtin_amdgcn_rcpf(t + 1.f);  // NaN-free for t in [0, inf]
}

#define NROWS 32832   // 513 seqs * 64 steps

// ---------- K0: repack concat_w into cw4[k4][d][4] ----------
__global__ __launch_bounds__(256)
void k0_cw4(const float* __restrict__ cw, float* __restrict__ cw4) {
  int idx = blockIdx.x * 256 + threadIdx.x;
  if (idx < 320000) {
    int d = idx / 1600, k = idx % 1600;
    cw4[(size_t)(k >> 2) * 800 + d * 4 + (k & 3)] = cw[idx];
  }
}

// ---------- K1: gather emb rows + input projection GEMM (f32) ----------
// Output column order PERMUTED: col = dir*400 + m*4 + g  (g = torch gate i,f,g,o)
// XP[r][col] = (wih[g*100+m] . x_r) + bih[g*100+m] + bhh[g*100+m], stored f16.
__global__ __launch_bounds__(128)
void k1_proj(const int* __restrict__ head_toks, const int* __restrict__ body_toks,
             const float* __restrict__ emb,
             const float* __restrict__ wihf, const float* __restrict__ wihb,
             const float* __restrict__ bihf, const float* __restrict__ bhhf,
             const float* __restrict__ bihb, const float* __restrict__ bhhb,
             _Float16* __restrict__ XP) {
  __shared__ float At[32][132];
  __shared__ float Wt[32][132];
  __shared__ int toks[128];
  const int tid = threadIdx.x;
  const int r0 = blockIdx.x * 128;
  const int c0 = blockIdx.y * 128;
  if (tid < 128) {
    int r = r0 + tid;
    int tok = 0;
    if (r < NROWS) {
      int u = r >> 6, t = r & 63;
      tok = (u < 512) ? body_toks[u * 64 + t] : head_toks[t];
    }
    toks[tid] = tok;
  }
  const int ty = tid >> 3;  // 0..15 -> rows ty*8..+7
  const int tx = tid & 7;   // 0..7  -> cols tx*4 + q*32 + j
  float acc[8][16];
#pragma unroll
  for (int i = 0; i < 8; ++i)
#pragma unroll
    for (int j = 0; j < 16; ++j) acc[i][j] = 0.f;

  for (int k0 = 0; k0 < 300; k0 += 32) {
    __syncthreads();
#pragma unroll
    for (int it = 0; it < 8; ++it) {  // stage A (gathered, transposed)
      int slot = tid + it * 128;
      int rr = slot >> 3, kq = slot & 7;
      int k = k0 + kq * 4;
      float4 v = make_float4(0.f, 0.f, 0.f, 0.f);
      if (k < 300) v = *(const float4*)(emb + (size_t)toks[rr] * 300 + k);
      At[kq * 4 + 0][rr] = v.x; At[kq * 4 + 1][rr] = v.y;
      At[kq * 4 + 2][rr] = v.z; At[kq * 4 + 3][rr] = v.w;
    }
#pragma unroll
    for (int it = 0; it < 8; ++it) {  // stage W (transposed, permuted rows)
      int slot = tid + it * 128;
      int cc = slot >> 3, kq = slot & 7;
      int gc = c0 + cc;
      int k = k0 + kq * 4;
      float4 v = make_float4(0.f, 0.f, 0.f, 0.f);
      if (k < 300 && gc < 800) {
        int dir = gc >= 400;
        int rem = gc - dir * 400;
        int orow = (rem & 3) * 100 + (rem >> 2);   // g*100 + m
        const float* wp = dir ? (wihb + (size_t)orow * 300)
                              : (wihf + (size_t)orow * 300);
        v = *(const float4*)(wp + k);
      }
      Wt[kq * 4 + 0][cc] = v.x; Wt[kq * 4 + 1][cc] = v.y;
      Wt[kq * 4 + 2][cc] = v.z; Wt[kq * 4 + 3][cc] = v.w;
    }
    __syncthreads();
#pragma unroll 4
    for (int k = 0; k < 32; ++k) {
      float a[8], b[16];
      *(float4*)&a[0] = *(const float4*)&At[k][ty * 8];
      *(float4*)&a[4] = *(const float4*)&At[k][ty * 8 + 4];
#pragma unroll
      for (int q = 0; q < 4; ++q)
        *(float4*)&b[q * 4] = *(const float4*)&Wt[k][tx * 4 + q * 32];
#pragma unroll
      for (int i = 0; i < 8; ++i)
#pragma unroll
        for (int j = 0; j < 16; ++j)
          acc[i][j] = fmaf(a[i], b[j], acc[i][j]);
    }
  }
  float biasv[16];
#pragma unroll
  for (int j = 0; j < 16; ++j) {
    int gc = c0 + tx * 4 + (j >> 2) * 32 + (j & 3);
    float bv = 0.f;
    if (gc < 800) {
      int dir = gc >= 400;
      int rem = gc - dir * 400;
      int orow = (rem & 3) * 100 + (rem >> 2);
      bv = dir ? (bihb[orow] + bhhb[orow]) : (bihf[orow] + bhhf[orow]);
    }
    biasv[j] = bv;
  }
#pragma unroll
  for (int i = 0; i < 8; ++i) {
    int r = r0 + ty * 8 + i;
    if (r >= NROWS) continue;
#pragma unroll
    for (int q = 0; q < 4; ++q) {
      int colq = c0 + tx * 4 + q * 32;
      if (colq >= 800) continue;
      half4 pk;
      pk[0] = (_Float16)(acc[i][q * 4 + 0] + biasv[q * 4 + 0]);
      pk[1] = (_Float16)(acc[i][q * 4 + 1] + biasv[q * 4 + 1]);
      pk[2] = (_Float16)(acc[i][q * 4 + 2] + biasv[q * 4 + 2]);
      pk[3] = (_Float16)(acc[i][q * 4 + 3] + biasv[q * 4 + 3]);
      *(half4*)(XP + (size_t)r * 800 + colq) = pk;
    }
  }
}

// ---------- K2: batched MFMA LSTM recurrence ----------
// Block = 16 units (one direction), 4 waves. whh register-resident as MFMA
// A-frags with padded rows ordered row = m*4 + gate  (M=448, K=128 padded).
// C layout puts all 4 gates of (u, m) in one lane's 4 C regs -> pointwise
// update is lane-local. H kept in LDS [16][128] f16, XOR-swizzled; XP tile
// double-buffered in LDS with 1-step-ahead prefetch.
#define XPL_ROW 1616                 // bytes per unit row (808 halves, pad)
#define XPL_BUF (16 * XPL_ROW)       // 25856 B
#define K2_LDS (4096 + 2 * XPL_BUF)  // H (16*128*2) + 2 XP buffers = 55808 B

__global__ __launch_bounds__(256, 1)
void k2_lstm(const _Float16* __restrict__ XP,
             const float* __restrict__ whhf, const float* __restrict__ whhb,
             float* __restrict__ sentRM, float* __restrict__ sentT,
             float* __restrict__ dout) {
  __shared__ char smem[K2_LDS];
  _Float16* H = (_Float16*)smem;                 // [16][128] f16, swizzled
  char* XPL = smem + 4096;                       // 2 x [16][XPL_ROW]
  const int tid = threadIdx.x;
  const int w = tid >> 6;      // wave 0..3
  const int l = tid & 63;
  const int b = blockIdx.x;    // 0..65
  const bool fwd = b < 33;
  const int bb = fwd ? b : b - 33;
  const float* whh = fwd ? whhf : whhb;
  const int seq0 = bb * 16;
  const int xoff = fwd ? 0 : 400;  // column offset within XP row
  const int doff = fwd ? 0 : 100;
  const int u = l & 15;        // unit column owned by this lane
  const int kq = l >> 4;       // 0..3

  // ---- load whh A-fragments into registers (once) ----
  half8 afrag[7][4];
#pragma unroll
  for (int mtl = 0; mtl < 7; ++mtl) {
    int gr = (w * 7 + mtl) * 16 + u;      // padded global row = m*4 + g
    int m = gr >> 2, g = gr & 3;
#pragma unroll
    for (int kt = 0; kt < 4; ++kt) {
      half8 v;
#pragma unroll
      for (int i = 0; i < 8; ++i) {
        int kk = kt * 32 + kq * 8 + i;
        float x = (m < 100 && kk < 100) ? whh[(size_t)(g * 100 + m) * 100 + kk] : 0.f;
        v[i] = (_Float16)x;
      }
      afrag[mtl][kt] = v;
    }
  }

  // zero H (pads stay zero forever)
  for (int i = tid; i < 2048; i += 256) H[i] = (_Float16)0.f;

  // XP tile staging: 16 rows x 1600 B -> XPL[buf], rows padded to XPL_ROW
  auto stage = [&](int t, int buf) {
    int tidx = fwd ? t : 63 - t;
#pragma unroll
    for (int it = 0; it < 7; ++it) {
      int idx = it * 64 + l;            // 0..447, valid < 400
      if (idx < 400) {
        int ul = 4 * w + idx / 100;     // unit row 0..15
        int ch = idx % 100;             // 16B chunk within 1600B row
        int seq = seq0 + ul; if (seq > 512) seq = 512;
        half8 v = *(const half8*)(XP + ((size_t)seq * 64 + tidx) * 800 + ch * 8);
        *(half8*)(XPL + buf * XPL_BUF + ul * XPL_ROW + ch * 16) = v;
      }
    }
  };
  stage(0, 0);
  __syncthreads();

  float cst[7], hst[7];
#pragma unroll
  for (int i = 0; i < 7; ++i) { cst[i] = 0.f; hst[i] = 0.f; }

  const int hswz = (u & 7) << 4;   // XOR swizzle for H rows (16B slots)

  for (int t = 0; t < 64; ++t) {
    const int buf = t & 1;
    if (t + 1 < 64) stage(t + 1, buf ^ 1);   // prefetch next XP tile

    // B-frags: lane l reads H[u][kt*32 + kq*8 .. +7]  (16B, swizzled)
    half8 bfrag[4];
#pragma unroll
    for (int kt = 0; kt < 4; ++kt) {
      int byte = u * 256 + ((kt * 64 + kq * 16) ^ hswz);
      bfrag[kt] = *(const half8*)((char*)H + byte);
    }
    f32x4 c[7];
#pragma unroll
    for (int mtl = 0; mtl < 7; ++mtl) {
      f32x4 acc = {0.f, 0.f, 0.f, 0.f};
#pragma unroll
      for (int kt = 0; kt < 4; ++kt)
        acc = __builtin_amdgcn_mfma_f32_16x16x32_f16(afrag[mtl][kt], bfrag[kt], acc, 0, 0, 0);
      c[mtl] = acc;
    }
    __syncthreads();   // all H reads done before any h write

    // pointwise: lane owns (u, m) with all 4 gates in c[mtl][0..3]
#pragma unroll
    for (int mtl = 0; mtl < 7; ++mtl) {
      int m = (w * 7 + mtl) * 4 + kq;   // 0..111
      if (m < 100) {
        half4 xp = *(const half4*)(XPL + buf * XPL_BUF + u * XPL_ROW + (xoff + m * 4) * 2);
        float pi = c[mtl][0] + (float)xp[0];
        float pf = c[mtl][1] + (float)xp[1];
        float pg = c[mtl][2] + (float)xp[2];
        float po = c[mtl][3] + (float)xp[3];
        float i_ = sigf(pi), f_ = sigf(pf), o_ = sigf(po);
        float g_ = tanhf_(pg);
        float cc = f_ * cst[mtl] + i_ * g_;
        cst[mtl] = cc;
        float h = o_ * tanhf_(cc);
        hst[mtl] = h;
        int byte = u * 256 + ((m * 2) ^ hswz);
        *(_Float16*)((char*)H + byte) = (_Float16)h;
      }
    }
    __syncthreads();   // h writes visible before next step's B-frag reads
  }

  // final h -> outputs
  const int seq = seq0 + u;
  if (seq <= 512) {
#pragma unroll
    for (int mtl = 0; mtl < 7; ++mtl) {
      int m = (w * 7 + mtl) * 4 + kq;
      if (m < 100) {
        int d = doff + m;
        float h = hst[mtl];
        sentRM[(size_t)seq * 200 + d] = h;
        sentT[(size_t)d * 520 + seq] = h;
        if (seq == 512) dout[200 + d] = h;
      }
    }
  }
}

// ---------- K3: Q/K/V projections. QT,KT stored [h][e][s]; V stored [h][t][e] ----------
__global__ __launch_bounds__(256)
void k3_qkv(const float* __restrict__ sentT,
            const float* __restrict__ wq, const float* __restrict__ bq,
            const float* __restrict__ wk, const float* __restrict__ bk,
            const float* __restrict__ wv, const float* __restrict__ bv,
            float* __restrict__ QT, float* __restrict__ KT, float* __restrict__ V) {
  __shared__ float slds[32 * 64];
  __shared__ float wt[32 * 204];
  const int tid = threadIdx.x;
  const int mat = blockIdx.x;
  const int h = blockIdx.y;
  const int s0 = blockIdx.z * 64;
  const float* W = (mat == 0) ? wq : (mat == 1) ? wk : wv;
  const float* B = (mat == 0) ? bq : (mat == 1) ? bk : bv;
  W += (size_t)h * 40000;
  B += h * 200;
  const int ts = (tid < 200) ? tid / 25 : 0;
  const int te = (tid < 200) ? tid % 25 : 0;
  float acc[8][8];
#pragma unroll
  for (int i = 0; i < 8; ++i)
#pragma unroll
    for (int j = 0; j < 8; ++j) acc[i][j] = 0.f;

  for (int d0 = 0; d0 < 200; d0 += 32) {
    __syncthreads();
#pragma unroll
    for (int it = 0; it < 8; ++it) {
      int idx = tid + it * 256;
      int dd = idx >> 6, sl = idx & 63;
      int d = d0 + dd;
      slds[idx] = (d < 200) ? sentT[(size_t)d * 520 + s0 + sl] : 0.f;
    }
    for (int idx = tid; idx < 1600; idx += 256) {
      int dq = idx / 200, e = idx % 200;
      int d = d0 + dq * 4;
      float4 v = make_float4(0.f, 0.f, 0.f, 0.f);
      if (d < 200) v = *(const float4*)(W + (size_t)e * 200 + d);
      wt[(dq * 4 + 0) * 204 + e] = v.x; wt[(dq * 4 + 1) * 204 + e] = v.y;
      wt[(dq * 4 + 2) * 204 + e] = v.z; wt[(dq * 4 + 3) * 204 + e] = v.w;
    }
    __syncthreads();
    if (tid < 200) {
#pragma unroll 4
      for (int dd = 0; dd < 32; ++dd) {
        float a[8], b[8];
        *(float4*)&a[0] = *(const float4*)&slds[dd * 64 + ts * 8];
        *(float4*)&a[4] = *(const float4*)&slds[dd * 64 + ts * 8 + 4];
        *(float4*)&b[0] = *(const float4*)&wt[dd * 204 + te * 8];
        *(float4*)&b[4] = *(const float4*)&wt[dd * 204 + te * 8 + 4];
#pragma unroll
        for (int i = 0; i < 8; ++i)
#pragma unroll
          for (int j = 0; j < 8; ++j) acc[i][j] = fmaf(a[i], b[j], acc[i][j]);
      }
    }
  }
  if (tid < 200) {
    if (mat < 2) {
      float* O = (mat == 0) ? QT : KT;
#pragma unroll
      for (int j = 0; j < 8; ++j) {
        int e = te * 8 + j;
        float bb = B[e];
        float vals[8];
#pragma unroll
        for (int i = 0; i < 8; ++i) vals[i] = acc[i][j] + bb;
        float* p = O + (size_t)h * 102400 + (size_t)e * 512 + s0 + ts * 8;
        *(float4*)&p[0] = *(float4*)&vals[0];
        *(float4*)&p[4] = *(float4*)&vals[4];
      }
    } else {
#pragma unroll
      for (int i = 0; i < 8; ++i) {
        float vals[8];
#pragma unroll
        for (int j = 0; j < 8; ++j) vals[j] = acc[i][j] + B[te * 8 + j];
        float* p = V + (size_t)h * 102400 + (size_t)(s0 + ts * 8 + i) * 200 + te * 8;
        *(float4*)&p[0] = *(float4*)&vals[0];
        *(float4*)&p[4] = *(float4*)&vals[4];
      }
    }
  }
}

// ---------- K4: SIMT[h][t][s] = Q[h,s,:] . K[h,t,:] ----------
__global__ __launch_bounds__(128)
void k4_sim(const float* __restrict__ QT, const float* __restrict__ KT,
            float* __restrict__ SIMT) {
  __shared__ float kt[32 * 64];
  __shared__ float qt[32 * 64];
  const int tid = threadIdx.x;
  const int s0 = blockIdx.x * 64;
  const int t0 = blockIdx.y * 64;
  const int h = blockIdx.z;
  const int tt = tid & 15, ss = tid >> 4;
  float acc[4][8];
#pragma unroll
  for (int i = 0; i < 4; ++i)
#pragma unroll
    for (int j = 0; j < 8; ++j) acc[i][j] = 0.f;
  for (int e0 = 0; e0 < 200; e0 += 32) {
    __syncthreads();
#pragma unroll
    for (int it = 0; it < 16; ++it) {
      int idx = tid + it * 128;
      int ee = idx >> 6, tl = idx & 63;
      int e = e0 + ee;
      kt[idx] = (e < 200) ? KT[(size_t)h * 102400 + (size_t)e * 512 + t0 + tl] : 0.f;
      qt[idx] = (e < 200) ? QT[(size_t)h * 102400 + (size_t)e * 512 + s0 + tl] : 0.f;
    }
    __syncthreads();
#pragma unroll 4
    for (int ee = 0; ee < 32; ++ee) {
      float a[4], b[8];
      *(float4*)&a[0] = *(const float4*)&kt[ee * 64 + tt * 4];
      *(float4*)&b[0] = *(const float4*)&qt[ee * 64 + ss * 8];
      *(float4*)&b[4] = *(const float4*)&qt[ee * 64 + ss * 8 + 4];
#pragma unroll
      for (int i = 0; i < 4; ++i)
#pragma unroll
        for (int j = 0; j < 8; ++j) acc[i][j] = fmaf(a[i], b[j], acc[i][j]);
    }
  }
#pragma unroll
  for (int i = 0; i < 4; ++i) {
    float* p = SIMT + ((size_t)h * 512 + t0 + tt * 4 + i) * 512 + s0 + ss * 8;
    *(float4*)&p[0] = *(float4*)&acc[i][0];
    *(float4*)&p[4] = *(float4*)&acc[i][4];
  }
}

// ---------- K5: softmax over s (contiguous rows of SIMT), in place ----------
__global__ __launch_bounds__(256)
void k5_softmax(float* __restrict__ SIMT) {
  const int tid = threadIdx.x;
  const int row = blockIdx.x * 4 + (tid >> 6);
  const int lane = tid & 63;
  float* p = SIMT + (size_t)row * 512 + lane * 8;
  float4 a = *(float4*)p, b = *(float4*)(p + 4);
  const float sc = 0.07071067811865475f;  // 1/sqrt(200)
  float v[8] = {a.x, a.y, a.z, a.w, b.x, b.y, b.z, b.w};
#pragma unroll
  for (int i = 0; i < 8; ++i) v[i] *= sc;
  float m = v[0];
#pragma unroll
  for (int i = 1; i < 8; ++i) m = fmaxf(m, v[i]);
  for (int d = 1; d < 64; d <<= 1) m = fmaxf(m, __shfl_xor(m, d, 64));
  float sum = 0.f;
#pragma unroll
  for (int i = 0; i < 8; ++i) { v[i] = __expf(v[i] - m); sum += v[i]; }
  for (int d = 1; d < 64; d <<= 1) sum += __shfl_xor(sum, d, 64);
  float inv = __builtin_amdgcn_rcpf(sum);
  a = make_float4(v[0] * inv, v[1] * inv, v[2] * inv, v[3] * inv);
  b = make_float4(v[4] * inv, v[5] * inv, v[6] * inv, v[7] * inv);
  *(float4*)p = a;
  *(float4*)(p + 4) = b;
}

// ---------- K6: OUT[h][s][e] = sum_t ATT[h][t][s] * V[h][t][e] ----------
__global__ __launch_bounds__(256)
void k6_av(const float* __restrict__ ATT, const float* __restrict__ V,
           float* __restrict__ OUTb) {
  __shared__ float attl[64 * 36];
  __shared__ float vl[64 * 204];
  const int tid = threadIdx.x;
  const int s0 = blockIdx.x * 32;
  const int h = blockIdx.y;
  const int ts = (tid < 200) ? tid / 25 : 0;
  const int te = (tid < 200) ? tid % 25 : 0;
  float acc[4][8];
#pragma unroll
  for (int i = 0; i < 4; ++i)
#pragma unroll
    for (int j = 0; j < 8; ++j) acc[i][j] = 0.f;
  for (int t0 = 0; t0 < 512; t0 += 64) {
    __syncthreads();
#pragma unroll
    for (int it = 0; it < 8; ++it) {
      int idx = tid + it * 256;
      int tl = idx >> 5, sl = idx & 31;
      attl[tl * 36 + sl] = ATT[((size_t)h * 512 + t0 + tl) * 512 + s0 + sl];
    }
    for (int idx = tid; idx < 12800; idx += 256) {
      int tl = idx / 200, e = idx % 200;
      vl[tl * 204 + e] = V[(size_t)h * 102400 + (size_t)(t0 + tl) * 200 + e];
    }
    __syncthreads();
    if (tid < 200) {
#pragma unroll 2
      for (int tl = 0; tl < 64; ++tl) {
        float a[4], b[8];
        *(float4*)&a[0] = *(const float4*)&attl[tl * 36 + ts * 4];
        *(float4*)&b[0] = *(const float4*)&vl[tl * 204 + te * 8];
        *(float4*)&b[4] = *(const float4*)&vl[tl * 204 + te * 8 + 4];
#pragma unroll
        for (int i = 0; i < 4; ++i)
#pragma unroll
          for (int j = 0; j < 8; ++j) acc[i][j] = fmaf(a[i], b[j], acc[i][j]);
      }
    }
  }
  if (tid < 200) {
#pragma unroll
    for (int i = 0; i < 4; ++i) {
      float* p = OUTb + (size_t)h * 102400 + (size_t)(s0 + ts * 4 + i) * 200 + te * 8;
      *(float4*)&p[0] = *(float4*)&acc[i][0];
      *(float4*)&p[4] = *(float4*)&acc[i][4];
    }
  }
}

// ---------- K7: multi[s][d], 8 sentences per block ----------
__global__ __launch_bounds__(256)
void k7_multi(const float* __restrict__ OUTb, const float* __restrict__ cw4,
              const float* __restrict__ concat_b, float* __restrict__ multi) {
  __shared__ float hc[8][1600];
  const int tid = threadIdx.x;
  const int s0 = blockIdx.x * 8;
  for (int idx = tid; idx < 12800; idx += 256) {
    int sl = idx / 1600, k = idx % 1600;
    int h = k / 200, e = k % 200;
    hc[sl][k] = OUTb[(size_t)h * 102400 + (size_t)(s0 + sl) * 200 + e];
  }
  __syncthreads();
  if (tid < 200) {
    float acc[8];
    float bb = concat_b[tid];
#pragma unroll
    for (int s = 0; s < 8; ++s) acc[s] = bb;
    const float4* cp = (const float4*)cw4 + tid;
    for (int k4 = 0; k4 < 400; ++k4) {
      float4 wv = cp[(size_t)k4 * 200];
#pragma unroll
      for (int s = 0; s < 8; ++s) {
        float4 x = *(const float4*)&hc[s][k4 * 4];
        acc[s] = fmaf(wv.x, x.x, acc[s]); acc[s] = fmaf(wv.y, x.y, acc[s]);
        acc[s] = fmaf(wv.z, x.z, acc[s]); acc[s] = fmaf(wv.w, x.w, acc[s]);
      }
    }
#pragma unroll
    for (int s = 0; s < 8; ++s) multi[(size_t)(s0 + s) * 200 + tid] = acc[s];
  }
}

// ---------- K8: high_sent_feature[d] = feat_b[d] + feat_w[d,:] . multi_flat ----------
__global__ __launch_bounds__(256)
void k8_feat(const float* __restrict__ feat_w, const float* __restrict__ feat_b,
             const float* __restrict__ multi, float* __restrict__ dout) {
  __shared__ float red[4];
  const int tid = threadIdx.x;
  const int d = blockIdx.x;
  const float4* fw = (const float4*)(feat_w + (size_t)d * 102400);
  const float4* mf = (const float4*)multi;
  float a = 0.f;
  for (int i = tid; i < 25600; i += 256) {
    float4 w = fw[i], x = mf[i];
    a = fmaf(w.x, x.x, a); a = fmaf(w.y, x.y, a);
    a = fmaf(w.z, x.z, a); a = fmaf(w.w, x.w, a);
  }
  for (int m_ = 1; m_ < 64; m_ <<= 1) a += __shfl_xor(a, m_, 64);
  if ((tid & 63) == 0) red[tid >> 6] = a;
  __syncthreads();
  if (tid == 0) dout[d] = red[0] + red[1] + red[2] + red[3] + feat_b[d];
}

// ---------- K9: TextCNN conv + maxpool ----------
struct ConvPtrs { const float* p[7]; };

__global__ __launch_bounds__(256)
void k9_conv(ConvPtrs cp, const float* __restrict__ conv_b,
             const float* __restrict__ sent, float* __restrict__ dout) {
  __shared__ float cwl[7 * 200];
  __shared__ float wmax[4];
  const int tid = threadIdx.x;
  const int wi = blockIdx.x;
  const int f = blockIdx.y;
  const int w = wi + 1;
  const float* cw = cp.p[wi] + (size_t)f * w * 200;
  for (int idx = tid; idx < w * 200; idx += 256) cwl[idx] = cw[idx];
  __syncthreads();
  const int wave = tid >> 6, lane = tid & 63;
  float best = -3.4e38f;
  for (int jj = wave; jj < 512 + w - 1; jj += 4) {
    float part = 0.f;
    for (int k = 0; k < w; ++k) {
      int r = jj + k - (w - 1);
      if (r >= 0 && r < 512) {
        const float* sr = sent + (size_t)r * 200;
        const float* cr = cwl + k * 200;
        for (int d = lane; d < 200; d += 64) part = fmaf(cr[d], sr[d], part);
      }
    }
    for (int m_ = 1; m_ < 64; m_ <<= 1) part += __shfl_xor(part, m_, 64);
    best = fmaxf(best, part);
  }
  if (lane == 0) wmax[wave] = best;
  __syncthreads();
  if (tid == 0) {
    float m = fmaxf(fmaxf(wmax[0], wmax[1]), fmaxf(wmax[2], wmax[3]));
    dout[400 + wi * 10 + f] = m + conv_b[wi * 10 + f];
  }
}

// ---------- host ----------
extern "C" void kernel_launch(void* const* d_in, const int* in_sizes, int n_in,
                              void* d_out, int out_size, void* d_ws, size_t ws_size,
                              hipStream_t stream) {
  (void)in_sizes; (void)n_in; (void)out_size; (void)ws_size;
  const int*   head_toks = (const int*)d_in[0];
  const int*   body_toks = (const int*)d_in[1];
  const float* emb      = (const float*)d_in[2];
  const float* wih_f    = (const float*)d_in[3];
  const float* whh_f    = (const float*)d_in[4];
  const float* bih_f    = (const float*)d_in[5];
  const float* bhh_f    = (const float*)d_in[6];
  const float* wih_b    = (const float*)d_in[7];
  const float* whh_b    = (const float*)d_in[8];
  const float* bih_b    = (const float*)d_in[9];
  const float* bhh_b    = (const float*)d_in[10];
  const float* wq       = (const float*)d_in[11];
  const float* bq       = (const float*)d_in[12];
  const float* wk       = (const float*)d_in[13];
  const float* bk       = (const float*)d_in[14];
  const float* wv       = (const float*)d_in[15];
  const float* bv       = (const float*)d_in[16];
  const float* concat_w = (const float*)d_in[17];
  const float* concat_b = (const float*)d_in[18];
  const float* feat_w   = (const float*)d_in[19];
  const float* feat_b   = (const float*)d_in[20];
  const float* conv_b   = (const float*)d_in[21];
  float* out = (float*)d_out;
  char* ws = (char*)d_ws;

  size_t off = 0;
  auto take = [&](size_t b) { size_t o = off; off += (b + 255) & ~(size_t)255; return o; };
  _Float16* XP  = (_Float16*)(ws + take(32832UL * 800 * 2));
  float* sentRM = (float*)(ws + take(513UL * 200 * 4));
  float* sentT  = (float*)(ws + take(200UL * 520 * 4));
  float* QT     = (float*)(ws + take(8UL * 200 * 512 * 4));
  float* KT     = (float*)(ws + take(8UL * 200 * 512 * 4));
  float* Vb     = (float*)(ws + take(8UL * 512 * 200 * 4));
  float* SIMT   = (float*)(ws + take(8UL * 512 * 512 * 4));
  float* OUTb   = (float*)(ws + take(8UL * 512 * 200 * 4));
  float* multi  = (float*)(ws + take(512UL * 200 * 4));
  float* cw4    = (float*)(ws + take(1600UL * 200 * 4));

  k0_cw4<<<1250, 256, 0, stream>>>(concat_w, cw4);
  k1_proj<<<dim3(257, 7), 128, 0, stream>>>(head_toks, body_toks, emb,
                                            wih_f, wih_b, bih_f, bhh_f, bih_b, bhh_b, XP);
  k2_lstm<<<66, 256, 0, stream>>>(XP, whh_f, whh_b, sentRM, sentT, out);
  k3_qkv<<<dim3(3, 8, 8), 256, 0, stream>>>(sentT, wq, bq, wk, bk, wv, bv, QT, KT, Vb);
  k4_sim<<<dim3(8, 8, 8), 128, 0, stream>>>(QT, KT, SIMT);
  k5_softmax<<<1024, 256, 0, stream>>>(SIMT);
  k6_av<<<dim3(16, 8), 256, 0, stream>>>(SIMT, Vb, OUTb);
  k7_multi<<<64, 256, 0, stream>>>(OUTb, cw4, concat_b, multi);
  k8_feat<<<200, 256, 0, stream>>>(feat_w, feat_b, multi, out);
  ConvPtrs cps;
  for (int i = 0; i < 7; ++i) cps.p[i] = (const float*)d_in[22 + i];
  k9_conv<<<dim3(7, 10), 256, 0, stream>>>(cps, conv_b, sentRM, out);
}